// Round 16
// baseline (263.371 us; speedup 1.0000x reference)
//
#include <hip/hip_runtime.h>
#include <stdint.h>

#define D_  64
#define DP1 65
#define M_  512
#define N_  4096

typedef float f32x4 __attribute__((ext_vector_type(4)));
typedef _Float16 h8 __attribute__((ext_vector_type(8)));

// ---------------- merged prep: symA/sumK2 | K1 cvt+transpose | K0T | opening ----------
__global__ void prepk(const float* __restrict__ A, const float* __restrict__ K0,
                      const float* __restrict__ K1, const float* __restrict__ x,
                      const float* __restrict__ tptr, const float* __restrict__ b0,
                      float* symA, float* sumK2,
                      _Float16* K1h, _Float16* K1Th, _Float16* K0Th,
                      _Float16* u0h, _Float16* ah, float* trH0){
  __shared__ float shm[2*64*66];
  int b = blockIdx.x;
  int t = threadIdx.x;
  if (b == 0){
    for (int idx = t; idx < DP1*DP1; idx += 256){
      int e = idx / DP1, d = idx % DP1;
      float s = 0.f;
      for (int r = 0; r < 10; ++r) s += A[r*DP1+e]*A[r*DP1+d];
      symA[idx] = s;
    }
    for (int m = t; m < M_; m += 256){
      float s = 0.f;
      for (int k = 0; k < D_; ++k){ float v = K0[m*DP1+k]; s += v*v; }
      sumK2[m] = s;
    }
  } else if (b < 65){
    int bb = b - 1;
    int r0 = (bb>>3)*64, c0 = (bb&7)*64;
    float* tile = shm;                       // [64][65]
    for (int it = 0; it < 16; ++it){
      int lin = it*256 + t;
      int r = lin >> 6, c = lin & 63;
      float v = K1[(r0+r)*M_ + c0+c];
      tile[r*65+c] = v;
      K1h[(r0+r)*M_ + c0+c] = (_Float16)v;
    }
    __syncthreads();
    for (int it = 0; it < 16; ++it){
      int lin = it*256 + t;
      int r = lin >> 6, c = lin & 63;
      K1Th[(c0+r)*M_ + (r0+c)] = (_Float16)tile[c*65+r];
    }
  } else if (b < 225){
    int idx = (b-65)*256 + t;
    if (idx < 80*M_){
      int d = idx / M_, i = idx % M_;
      float v = (d < DP1) ? K0[i*DP1 + d] : 0.f;
      K0Th[idx] = (_Float16)v;
    }
  } else {
    int bb = b - 225;
    int n0 = (bb & 63)*64, m0 = (bb >> 6)*64;
    float* sS = shm;                         // [64][66]
    float* sK = shm + 64*66;                 // [64][66]
    float tval = tptr[0];
    for (int it = 0; it < 17; ++it){
      int lin = it*256 + t;
      if (lin < 64*65){
        int r = lin/65, c = lin%65;
        sS[r*66+c] = (c < 64) ? x[(n0+r)*64 + c] : tval;
        sK[r*66+c] = K0[(m0+r)*DP1 + c];
      }
    }
    __syncthreads();
    int tn = (t>>4)*4, tm = (t&15)*4;
    float acc[4][4] = {};
    for (int e = 0; e < DP1; ++e){
      float sv[4], kv[4];
      for (int i=0;i<4;++i){ sv[i]=sS[(tn+i)*66+e]; kv[i]=sK[(tm+i)*66+e]; }
      for (int i=0;i<4;++i) for(int j=0;j<4;++j) acc[i][j] += sv[i]*kv[j];
    }
    for (int i=0;i<4;++i) for(int j=0;j<4;++j){
      int n = n0+tn+i, m = m0+tm+j;
      float o = acc[i][j] + b0[m];
      float a = tanhf(o);
      float ax = fabsf(o);
      float u0 = ax + log1pf(expf(-2.f*ax));
      u0h[n*M_+m] = (_Float16)u0;
      ah[n*M_+m]  = (_Float16)a;
    }
    if (m0 == 0 && t < 64) trH0[n0+t] = 0.f;
  }
}

// ---------------- 4096x512x512 GEMMs (MODE 0: lin1, MODE 1: z1) ----------------
template<int MODE>
__launch_bounds__(256, 2)
__global__ void gemm512(const _Float16* __restrict__ Ah, const _Float16* __restrict__ Wh,
                        const float* __restrict__ bias, const float* __restrict__ w,
                        const _Float16* __restrict__ ah, const float* __restrict__ sumK2,
                        _Float16* out0, _Float16* out1, float* trH0){
  __shared__ _Float16 sW[64*512];    // 64 KB, chunk-swizzled (c ^ (r&7))
  int n0 = blockIdx.x*64, i0 = blockIdx.y*64;
  int t = threadIdx.x;
  int wv = t>>6, l = t&63;
  int c15 = l & 15, g = l>>4;
  h8 af[16];
  {
    const _Float16* ap = Ah + (size_t)(n0 + wv*16 + c15)*M_ + g*8;
    #pragma unroll
    for (int tt = 0; tt < 16; ++tt) af[tt] = *(const h8*)(ap + tt*32);
  }
  #pragma unroll
  for (int it = 0; it < 16; ++it){
    int r = it*4 + wv;
    const _Float16* src = Wh + (size_t)(i0 + r)*M_ + ((l ^ (r & 7))*8);
    __builtin_amdgcn_global_load_lds(
        (const __attribute__((address_space(1))) void*)src,
        (__attribute__((address_space(3))) void*)(&sW[r*512]), 16, 0, 0);
  }
  __syncthreads();
  f32x4 zero = {0.f,0.f,0.f,0.f};
  f32x4 acc[4]; for (int k=0;k<4;++k) acc[k]=zero;
  #pragma unroll
  for (int step = 0; step < 16; ++step){
    int p0 = (((step*4 + g) ^ (c15 & 7))*8);
    h8 bf0 = *(const h8*)(&sW[(     c15)*512 + p0]);
    h8 bf1 = *(const h8*)(&sW[(16 + c15)*512 + p0]);
    h8 bf2 = *(const h8*)(&sW[(32 + c15)*512 + p0]);
    h8 bf3 = *(const h8*)(&sW[(48 + c15)*512 + p0]);
    h8 a = af[step];
    acc[0] = __builtin_amdgcn_mfma_f32_16x16x32_f16(a, bf0, acc[0], 0, 0, 0);
    acc[1] = __builtin_amdgcn_mfma_f32_16x16x32_f16(a, bf1, acc[1], 0, 0, 0);
    acc[2] = __builtin_amdgcn_mfma_f32_16x16x32_f16(a, bf2, acc[2], 0, 0, 0);
    acc[3] = __builtin_amdgcn_mfma_f32_16x16x32_f16(a, bf3, acc[3], 0, 0, 0);
  }
  if (MODE == 0){
    for (int kt=0;kt<4;++kt) for (int r=0;r<4;++r){
      int n = n0+wv*16+(l>>4)*4+r;
      int i = i0+kt*16+c15;
      float v = acc[kt][r] + bias[i];
      float tl = tanhf(v);
      out0[n*M_+i] = (_Float16)(tl*w[i]);
      out1[n*M_+i] = (_Float16)((1.f-tl*tl)*w[i]);
    }
  } else {
    for (int r=0;r<4;++r){
      int n = n0+wv*16+(l>>4)*4+r;
      float rowpart = 0.f;
      for (int kt=0;kt<4;++kt){
        int i = i0+kt*16+c15;
        float z1 = acc[kt][r] + w[i];
        float a = (float)ah[n*M_+i];
        out0[n*M_+i] = (_Float16)(a*z1);
        rowpart += (1.f-a*a)*z1*sumK2[i];
      }
      for (int m=1;m<16;m<<=1) rowpart += __shfl_xor(rowpart, m);
      if (c15==0) atomicAdd(&trH0[n], rowpart);
    }
  }
}

// ---------------- z0 partials = az1 @ K0 over K-quarter (N x 80, K=128) --------------
__launch_bounds__(256, 4)
__global__ void gemmz0(const _Float16* __restrict__ az1h, const _Float16* __restrict__ K0Th,
                       float* z0p){
  int n0 = blockIdx.x*64;
  int q  = blockIdx.y;               // K-quarter
  int t = threadIdx.x, wv = t>>6, l = t&63;
  int r15 = l & 15;
  int krow = q*128 + (l>>4)*8;
  const _Float16* abase = az1h + (size_t)(n0 + wv*16 + r15)*M_ + krow;
  const _Float16* kb0 = K0Th + (size_t)( 0 + r15)*M_ + krow;
  const _Float16* kb1 = K0Th + (size_t)(16 + r15)*M_ + krow;
  const _Float16* kb2 = K0Th + (size_t)(32 + r15)*M_ + krow;
  const _Float16* kb3 = K0Th + (size_t)(48 + r15)*M_ + krow;
  const _Float16* kb4 = K0Th + (size_t)(64 + r15)*M_ + krow;
  f32x4 zero = {0.f,0.f,0.f,0.f};
  f32x4 acc[5]; for (int k=0;k<5;++k) acc[k]=zero;
  #pragma unroll
  for (int ii = 0; ii < 4; ++ii){
    const int j0 = ii*32;
    h8 af = *(const h8*)(abase + j0);
    h8 b0c = *(const h8*)(kb0 + j0);
    h8 b1c = *(const h8*)(kb1 + j0);
    h8 b2c = *(const h8*)(kb2 + j0);
    h8 b3c = *(const h8*)(kb3 + j0);
    h8 b4c = *(const h8*)(kb4 + j0);
    acc[0] = __builtin_amdgcn_mfma_f32_16x16x32_f16(af, b0c, acc[0], 0, 0, 0);
    acc[1] = __builtin_amdgcn_mfma_f32_16x16x32_f16(af, b1c, acc[1], 0, 0, 0);
    acc[2] = __builtin_amdgcn_mfma_f32_16x16x32_f16(af, b2c, acc[2], 0, 0, 0);
    acc[3] = __builtin_amdgcn_mfma_f32_16x16x32_f16(af, b3c, acc[3], 0, 0, 0);
    acc[4] = __builtin_amdgcn_mfma_f32_16x16x32_f16(af, b4c, acc[4], 0, 0, 0);
  }
  float* zp = z0p + (size_t)q*N_*80;
  for (int dt=0; dt<5; ++dt) for (int r=0;r<4;++r){
    int n = n0+wv*16+(l>>4)*4+r;
    int d = dt*16+r15;
    zp[n*80+d] = acc[dt][r];
  }
}

// ---------------- dominant: t1 partials, 8-wave / 4 waves-per-SIMD variant -----------
// Same proven recipe (barrier-free loop, swizzled K1-in-LDS, reg-resident Kopen,
// packed-f16 a-fold) but tiled for occupancy: wave = k16 x i32 x s4, live set ~95
// regs (acc 32 + kf-half 32 + temps) under the 128-reg / 4-waves-per-SIMD cap.
// LDS 68KB -> 2 blocks/CU -> 16 waves/CU (2x latency hiding vs kjk13's 8).
// kf second half reloaded mid-loop (one L2-hot stall per block, ~300cyc).
__launch_bounds__(512, 4)
__global__ void kjk14(const _Float16* __restrict__ K1h, const _Float16* __restrict__ K0Th,
                      const _Float16* __restrict__ ah, const _Float16* __restrict__ ch,
                      float* trH0){
  __shared__ _Float16 sK1[64*512];   // 64 KB, chunk-swizzled (c ^ (r&7))
  __shared__ _Float16 sAv[4*512];    // 4 KB
  int t = threadIdx.x;
  int n0 = blockIdx.x*4;             // 4 samples
  int i0 = blockIdx.y*64;            // 64 K1 rows
  int wv = t>>6, l = t&63;
  int c15 = l & 15, g = l>>4;
  int ih = (wv&1)*32;                // wave's i-half within the 64-row tile
  int ks = wv>>1;                    // wave's k-slice 0..3
  const _Float16* kfp = K0Th + (size_t)(ks*16 + c15)*M_ + g*8;
  h8 kf[8];
  #pragma unroll
  for (int st = 0; st < 8; ++st) kf[st] = *(const h8*)(kfp + st*32);
  // stage K1 tile (8 waves x 8 iters), pre-swizzled source, linear LDS dest
  #pragma unroll
  for (int it = 0; it < 8; ++it){
    int r = it*8 + wv;
    const _Float16* src = K1h + (size_t)(i0 + r)*M_ + ((l ^ (r & 7))*8);
    __builtin_amdgcn_global_load_lds(
        (const __attribute__((address_space(1))) void*)src,
        (__attribute__((address_space(3))) void*)(&sK1[r*512]), 16, 0, 0);
  }
  // stage a-rows (4 x 512 = 256 chunks; threads 0..255)
  if (t < 256){
    int s = t>>6, c = t&63;
    *(h8*)(&sAv[s*512 + c*8]) = *(const h8*)(ah + (size_t)(n0+s)*M_ + c*8);
  }
  __syncthreads();
  f32x4 zero = {0.f,0.f,0.f,0.f};
  f32x4 acc[2][4];                   // [i-tile][sample]
  #pragma unroll
  for (int tt=0;tt<2;++tt)
    #pragma unroll
    for (int s=0;s<4;++s) acc[tt][s]=zero;
  #pragma unroll
  for (int step = 0; step < 8; ++step){
    int p0 = (((step*4 + g) ^ (c15 & 7))*8);
    h8 bf0 = *(const h8*)(&sK1[(ih +      c15)*512 + p0]);
    h8 bf1 = *(const h8*)(&sK1[(ih + 16 + c15)*512 + p0]);
    int aoff = step*32 + g*8;
    h8 k = kf[step];
    #pragma unroll
    for (int s = 0; s < 4; ++s){
      h8 av = *(const h8*)(&sAv[s*512 + aoff]);
      h8 ap = k*av;
      acc[0][s] = __builtin_amdgcn_mfma_f32_16x16x32_f16(ap, bf0, acc[0][s], 0, 0, 0);
      acc[1][s] = __builtin_amdgcn_mfma_f32_16x16x32_f16(ap, bf1, acc[1][s], 0, 0, 0);
    }
  }
  // reload second kf half (L2-hot; one latency exposure)
  #pragma unroll
  for (int st = 0; st < 8; ++st) kf[st] = *(const h8*)(kfp + (st+8)*32);
  #pragma unroll
  for (int step = 8; step < 16; ++step){
    int p0 = (((step*4 + g) ^ (c15 & 7))*8);
    h8 bf0 = *(const h8*)(&sK1[(ih +      c15)*512 + p0]);
    h8 bf1 = *(const h8*)(&sK1[(ih + 16 + c15)*512 + p0]);
    int aoff = step*32 + g*8;
    h8 k = kf[step-8];
    #pragma unroll
    for (int s = 0; s < 4; ++s){
      h8 av = *(const h8*)(&sAv[s*512 + aoff]);
      h8 ap = k*av;
      acc[0][s] = __builtin_amdgcn_mfma_f32_16x16x32_f16(ap, bf0, acc[0][s], 0, 0, 0);
      acc[1][s] = __builtin_amdgcn_mfma_f32_16x16x32_f16(ap, bf1, acc[1][s], 0, 0, 0);
    }
  }
  // epilogue: t1 += c_i * C[k,i]^2 over the wave's (k16 x i32) quadrant
  #pragma unroll
  for (int s = 0; s < 4; ++s){
    float part = 0.f;
    #pragma unroll
    for (int tt = 0; tt < 2; ++tt){
      float ci = (float)ch[(size_t)(n0+s)*M_ + i0 + ih + tt*16 + c15];
      f32x4 a = acc[tt][s];
      part += ci*(a[0]*a[0] + a[1]*a[1] + a[2]*a[2] + a[3]*a[3]);
    }
    for (int m=32;m>=1;m>>=1) part += __shfl_xor(part, m);
    if (l == 0) atomicAdd(&trH0[n0+s], part);
  }
}

// ---------------- final: grad, outputs (sums z0 partials; adds symA trace) ----------
__global__ void finalk(const float* __restrict__ x, const float* __restrict__ tptr,
                       const float* __restrict__ symA, const float* __restrict__ c_w,
                       const float* __restrict__ z0p, const float* __restrict__ trH0,
                       float* out){
  __shared__ float sA[DP1*DP1];
  int t = threadIdx.x;
  for (int i = t; i < DP1*DP1; i += 256) sA[i] = symA[i];
  __syncthreads();
  int wv = t>>6, l = t&63;
  int n = blockIdx.x*4 + wv;
  float tval = tptr[0];
  float sv = x[n*64 + l];
  float z0l = z0p[(size_t)0*N_*80 + n*80 + l] + z0p[(size_t)1*N_*80 + n*80 + l]
            + z0p[(size_t)2*N_*80 + n*80 + l] + z0p[(size_t)3*N_*80 + n*80 + l];
  float z0t = z0p[(size_t)0*N_*80 + n*80 + 64] + z0p[(size_t)1*N_*80 + n*80 + 64]
            + z0p[(size_t)2*N_*80 + n*80 + 64] + z0p[(size_t)3*N_*80 + n*80 + 64];
  float acc = z0l + c_w[l];
  for (int e = 0; e < 64; ++e){
    float se = __shfl(sv, e);
    acc += se * sA[l*DP1 + e];     // symA symmetric
  }
  acc += tval * sA[l*DP1 + 64];
  // trace(symA[:64,:64]) in-register
  float trd = sA[l*66];
  for (int m=32;m>=1;m>>=1) trd += __shfl_xor(trd, m);
  // grad[64]
  float g64 = sv * sA[64*DP1 + l];
  for (int m=32;m>=1;m>>=1) g64 += __shfl_xor(g64, m);
  g64 += tval*sA[64*DP1+64] + z0t + c_w[64];
  float dz = -acc;
  out[n*64 + l] = dz;
  float q = dz*dz;
  for (int m=32;m>=1;m>>=1) q += __shfl_xor(q, m);
  float costL = 0.5f*q;
  if (l == 0){
    out[N_*64 + n]        = -(trH0[n] + trd);
    out[N_*64 + N_ + n]   = costL;
    out[N_*64 + 2*N_ + n] = fabsf(-g64 + costL);
  }
}

extern "C" void kernel_launch(void* const* d_in, const int* in_sizes, int n_in,
                              void* d_out, int out_size, void* d_ws, size_t ws_size,
                              hipStream_t stream){
  const float* x   = (const float*)d_in[0];
  const float* tp  = (const float*)d_in[1];
  const float* K0  = (const float*)d_in[2];
  const float* b0  = (const float*)d_in[3];
  const float* K1  = (const float*)d_in[4];
  const float* b1  = (const float*)d_in[5];
  const float* w   = (const float*)d_in[6];
  const float* A   = (const float*)d_in[7];
  const float* c_w = (const float*)d_in[8];
  float* out = (float*)d_out;

  char* ws = (char*)d_ws;
  size_t off = 0;
  auto alloc = [&](size_t bytes)->void*{
    void* p = ws + off; off += bytes; off = (off + 255) & ~(size_t)255; return p;
  };
  _Float16* K1h   = (_Float16*)alloc(512*512*2);
  _Float16* K1Th  = (_Float16*)alloc(512*512*2);
  _Float16* K0Th  = (_Float16*)alloc(80*512*2);
  float* symA     = (float*)alloc(DP1*DP1*4);
  float* sumK2    = (float*)alloc(512*4);
  _Float16* u0h   = (_Float16*)alloc((size_t)N_*M_*2);
  _Float16* ah    = (_Float16*)alloc((size_t)N_*M_*2);
  _Float16* tl1wh = (_Float16*)alloc((size_t)N_*M_*2);
  _Float16* ch    = (_Float16*)alloc((size_t)N_*M_*2);
  _Float16* az1h  = (_Float16*)alloc((size_t)N_*M_*2);
  float* z0p      = (float*)alloc((size_t)4*N_*80*4);
  float* trH0     = (float*)alloc(N_*4);

  prepk<<<737, 256, 0, stream>>>(A, K0, K1, x, tp, b0, symA, sumK2,
                                 K1h, K1Th, K0Th, u0h, ah, trH0);
  gemm512<0><<<dim3(N_/64, M_/64), 256, 0, stream>>>(u0h, K1h, b1, w, nullptr, nullptr,
                                                     tl1wh, ch, nullptr);
  gemm512<1><<<dim3(N_/64, M_/64), 256, 0, stream>>>(tl1wh, K1Th, nullptr, w, ah, sumK2,
                                                     az1h, nullptr, trH0);
  gemmz0<<<dim3(N_/64, 4), 256, 0, stream>>>(az1h, K0Th, z0p);
  kjk14<<<dim3(N_/4, 8), 512, 0, stream>>>(K1h, K0Th, ah, ch, trH0);
  finalk<<<N_/4, 256, 0, stream>>>(x, tp, symA, c_w, z0p, trH0, out);
}

// Round 17
// 201.338 us; speedup vs baseline: 1.3081x; 1.3081x over previous
//
#include <hip/hip_runtime.h>
#include <stdint.h>

#define D_  64
#define DP1 65
#define M_  512
#define N_  4096

typedef float f32x4 __attribute__((ext_vector_type(4)));
typedef _Float16 h8 __attribute__((ext_vector_type(8)));

// ---------------- merged prep: symA/sumK2 | K1 cvt+transpose | K0T | opening ----------
__global__ void prepk(const float* __restrict__ A, const float* __restrict__ K0,
                      const float* __restrict__ K1, const float* __restrict__ x,
                      const float* __restrict__ tptr, const float* __restrict__ b0,
                      float* symA, float* sumK2,
                      _Float16* K1h, _Float16* K1Th, _Float16* K0Th,
                      _Float16* u0h, _Float16* ah, float* trH0){
  __shared__ float shm[2*64*66];
  int b = blockIdx.x;
  int t = threadIdx.x;
  if (b == 0){
    for (int idx = t; idx < DP1*DP1; idx += 256){
      int e = idx / DP1, d = idx % DP1;
      float s = 0.f;
      for (int r = 0; r < 10; ++r) s += A[r*DP1+e]*A[r*DP1+d];
      symA[idx] = s;
    }
    for (int m = t; m < M_; m += 256){
      float s = 0.f;
      for (int k = 0; k < D_; ++k){ float v = K0[m*DP1+k]; s += v*v; }
      sumK2[m] = s;
    }
  } else if (b < 65){
    int bb = b - 1;
    int r0 = (bb>>3)*64, c0 = (bb&7)*64;
    float* tile = shm;                       // [64][65]
    for (int it = 0; it < 16; ++it){
      int lin = it*256 + t;
      int r = lin >> 6, c = lin & 63;
      float v = K1[(r0+r)*M_ + c0+c];
      tile[r*65+c] = v;
      K1h[(r0+r)*M_ + c0+c] = (_Float16)v;
    }
    __syncthreads();
    for (int it = 0; it < 16; ++it){
      int lin = it*256 + t;
      int r = lin >> 6, c = lin & 63;
      K1Th[(c0+r)*M_ + (r0+c)] = (_Float16)tile[c*65+r];
    }
  } else if (b < 225){
    int idx = (b-65)*256 + t;
    if (idx < 80*M_){
      int d = idx / M_, i = idx % M_;
      float v = (d < DP1) ? K0[i*DP1 + d] : 0.f;
      K0Th[idx] = (_Float16)v;
    }
  } else {
    int bb = b - 225;
    int n0 = (bb & 63)*64, m0 = (bb >> 6)*64;
    float* sS = shm;                         // [64][66]
    float* sK = shm + 64*66;                 // [64][66]
    float tval = tptr[0];
    for (int it = 0; it < 17; ++it){
      int lin = it*256 + t;
      if (lin < 64*65){
        int r = lin/65, c = lin%65;
        sS[r*66+c] = (c < 64) ? x[(n0+r)*64 + c] : tval;
        sK[r*66+c] = K0[(m0+r)*DP1 + c];
      }
    }
    __syncthreads();
    int tn = (t>>4)*4, tm = (t&15)*4;
    float acc[4][4] = {};
    for (int e = 0; e < DP1; ++e){
      float sv[4], kv[4];
      for (int i=0;i<4;++i){ sv[i]=sS[(tn+i)*66+e]; kv[i]=sK[(tm+i)*66+e]; }
      for (int i=0;i<4;++i) for(int j=0;j<4;++j) acc[i][j] += sv[i]*kv[j];
    }
    for (int i=0;i<4;++i) for(int j=0;j<4;++j){
      int n = n0+tn+i, m = m0+tm+j;
      float o = acc[i][j] + b0[m];
      float a = tanhf(o);
      float ax = fabsf(o);
      float u0 = ax + log1pf(expf(-2.f*ax));
      u0h[n*M_+m] = (_Float16)u0;
      ah[n*M_+m]  = (_Float16)a;
    }
    if (m0 == 0 && t < 64) trH0[n0+t] = 0.f;
  }
}

// ---------------- 4096x512x512 GEMMs (MODE 0: lin1, MODE 1: z1) ----------------
// kjk-style: W tile (64x512, 64KB) staged once via global_load_lds w16 pre-swizzled
// src; A row-fragment af[16] (64 VGPRs) loaded once; barrier-free inner loop of
// 4 swizzled ds_read_b128 + 4 MFMA per step. Epilogues unchanged.
template<int MODE>
__launch_bounds__(256, 2)
__global__ void gemm512(const _Float16* __restrict__ Ah, const _Float16* __restrict__ Wh,
                        const float* __restrict__ bias, const float* __restrict__ w,
                        const _Float16* __restrict__ ah, const float* __restrict__ sumK2,
                        _Float16* out0, _Float16* out1, float* trH0){
  __shared__ _Float16 sW[64*512];    // 64 KB, chunk-swizzled (c ^ (r&7))
  int n0 = blockIdx.x*64, i0 = blockIdx.y*64;
  int t = threadIdx.x;
  int wv = t>>6, l = t&63;
  int c15 = l & 15, g = l>>4;
  // A fragment: wave's 16 n-rows slice (row = n0+wv*16+c15), all 512 j. loaded once.
  h8 af[16];
  {
    const _Float16* ap = Ah + (size_t)(n0 + wv*16 + c15)*M_ + g*8;
    #pragma unroll
    for (int tt = 0; tt < 16; ++tt) af[tt] = *(const h8*)(ap + tt*32);
  }
  // stage W tile: wave-uniform row r = it*4+wv; LDS chunk l (linear), src chunk l^(r&7)
  #pragma unroll
  for (int it = 0; it < 16; ++it){
    int r = it*4 + wv;
    const _Float16* src = Wh + (size_t)(i0 + r)*M_ + ((l ^ (r & 7))*8);
    __builtin_amdgcn_global_load_lds(
        (const __attribute__((address_space(1))) void*)src,
        (__attribute__((address_space(3))) void*)(&sW[r*512]), 16, 0, 0);
  }
  __syncthreads();
  f32x4 zero = {0.f,0.f,0.f,0.f};
  f32x4 acc[4]; for (int k=0;k<4;++k) acc[k]=zero;
  #pragma unroll
  for (int step = 0; step < 16; ++step){
    int p0 = (((step*4 + g) ^ (c15 & 7))*8);
    h8 bf0 = *(const h8*)(&sW[(     c15)*512 + p0]);
    h8 bf1 = *(const h8*)(&sW[(16 + c15)*512 + p0]);
    h8 bf2 = *(const h8*)(&sW[(32 + c15)*512 + p0]);
    h8 bf3 = *(const h8*)(&sW[(48 + c15)*512 + p0]);
    h8 a = af[step];
    acc[0] = __builtin_amdgcn_mfma_f32_16x16x32_f16(a, bf0, acc[0], 0, 0, 0);
    acc[1] = __builtin_amdgcn_mfma_f32_16x16x32_f16(a, bf1, acc[1], 0, 0, 0);
    acc[2] = __builtin_amdgcn_mfma_f32_16x16x32_f16(a, bf2, acc[2], 0, 0, 0);
    acc[3] = __builtin_amdgcn_mfma_f32_16x16x32_f16(a, bf3, acc[3], 0, 0, 0);
  }
  if (MODE == 0){
    for (int kt=0;kt<4;++kt) for (int r=0;r<4;++r){
      int n = n0+wv*16+(l>>4)*4+r;
      int i = i0+kt*16+c15;
      float v = acc[kt][r] + bias[i];
      float tl = tanhf(v);
      out0[n*M_+i] = (_Float16)(tl*w[i]);
      out1[n*M_+i] = (_Float16)((1.f-tl*tl)*w[i]);
    }
  } else {
    for (int r=0;r<4;++r){
      int n = n0+wv*16+(l>>4)*4+r;
      float rowpart = 0.f;
      for (int kt=0;kt<4;++kt){
        int i = i0+kt*16+c15;
        float z1 = acc[kt][r] + w[i];
        float a = (float)ah[n*M_+i];
        out0[n*M_+i] = (_Float16)(a*z1);
        rowpart += (1.f-a*a)*z1*sumK2[i];
      }
      for (int m=1;m<16;m<<=1) rowpart += __shfl_xor(rowpart, m);
      if (c15==0) atomicAdd(&trH0[n], rowpart);
    }
  }
}

// ---------------- z0 partials = az1 @ K0 over K-quarter (N x 80, K=128) --------------
__launch_bounds__(256, 4)
__global__ void gemmz0(const _Float16* __restrict__ az1h, const _Float16* __restrict__ K0Th,
                       float* z0p){
  int n0 = blockIdx.x*64;
  int q  = blockIdx.y;               // K-quarter
  int t = threadIdx.x, wv = t>>6, l = t&63;
  int r15 = l & 15;
  int krow = q*128 + (l>>4)*8;
  const _Float16* abase = az1h + (size_t)(n0 + wv*16 + r15)*M_ + krow;
  const _Float16* kb0 = K0Th + (size_t)( 0 + r15)*M_ + krow;
  const _Float16* kb1 = K0Th + (size_t)(16 + r15)*M_ + krow;
  const _Float16* kb2 = K0Th + (size_t)(32 + r15)*M_ + krow;
  const _Float16* kb3 = K0Th + (size_t)(48 + r15)*M_ + krow;
  const _Float16* kb4 = K0Th + (size_t)(64 + r15)*M_ + krow;
  f32x4 zero = {0.f,0.f,0.f,0.f};
  f32x4 acc[5]; for (int k=0;k<5;++k) acc[k]=zero;
  #pragma unroll
  for (int ii = 0; ii < 4; ++ii){
    const int j0 = ii*32;
    h8 af = *(const h8*)(abase + j0);
    h8 b0c = *(const h8*)(kb0 + j0);
    h8 b1c = *(const h8*)(kb1 + j0);
    h8 b2c = *(const h8*)(kb2 + j0);
    h8 b3c = *(const h8*)(kb3 + j0);
    h8 b4c = *(const h8*)(kb4 + j0);
    acc[0] = __builtin_amdgcn_mfma_f32_16x16x32_f16(af, b0c, acc[0], 0, 0, 0);
    acc[1] = __builtin_amdgcn_mfma_f32_16x16x32_f16(af, b1c, acc[1], 0, 0, 0);
    acc[2] = __builtin_amdgcn_mfma_f32_16x16x32_f16(af, b2c, acc[2], 0, 0, 0);
    acc[3] = __builtin_amdgcn_mfma_f32_16x16x32_f16(af, b3c, acc[3], 0, 0, 0);
    acc[4] = __builtin_amdgcn_mfma_f32_16x16x32_f16(af, b4c, acc[4], 0, 0, 0);
  }
  float* zp = z0p + (size_t)q*N_*80;
  for (int dt=0; dt<5; ++dt) for (int r=0;r<4;++r){
    int n = n0+wv*16+(l>>4)*4+r;
    int d = dt*16+r15;
    zp[n*80+d] = acc[dt][r];
  }
}

// ---------------- dominant: t1 partials (kjk11 exact: no setprio) --------------------
__launch_bounds__(256, 2)
__global__ void kjk13(const _Float16* __restrict__ K1h, const _Float16* __restrict__ K0Th,
                      const _Float16* __restrict__ ah, const _Float16* __restrict__ ch,
                      float* trH0){
  __shared__ _Float16 sK1[64*512];   // 64 KB, chunk-swizzled (c ^ (r&7))
  __shared__ _Float16 sAv[8*512];    // 8 KB
  int t = threadIdx.x;
  int n0 = blockIdx.x*8;             // 8 samples
  int i0 = blockIdx.y*64;            // 64 K1 rows
  int wv = t>>6, l = t&63;
  int c15 = l & 15, g = l>>4;
  h8 kf[16];
  {
    const _Float16* kfp = K0Th + (size_t)(wv*16 + c15)*M_ + g*8;
    #pragma unroll
    for (int tt = 0; tt < 16; ++tt) kf[tt] = *(const h8*)(kfp + tt*32);
  }
  #pragma unroll
  for (int it = 0; it < 16; ++it){
    int r = it*4 + wv;
    const _Float16* src = K1h + (size_t)(i0 + r)*M_ + ((l ^ (r & 7))*8);
    __builtin_amdgcn_global_load_lds(
        (const __attribute__((address_space(1))) void*)src,
        (__attribute__((address_space(3))) void*)(&sK1[r*512]), 16, 0, 0);
  }
  #pragma unroll
  for (int it = 0; it < 2; ++it){
    int cc = it*256 + t;
    int s = cc >> 6, c = cc & 63;
    *(h8*)(&sAv[s*512 + c*8]) = *(const h8*)(ah + (size_t)(n0+s)*M_ + c*8);
  }
  __syncthreads();
  f32x4 zero = {0.f,0.f,0.f,0.f};
  f32x4 acc[4][8];
  #pragma unroll
  for (int tt=0;tt<4;++tt)
    #pragma unroll
    for (int s=0;s<8;++s) acc[tt][s]=zero;
  #pragma unroll
  for (int step = 0; step < 16; ++step){
    int p0 = (((step*4 + g) ^ (c15 & 7))*8);
    h8 bf0 = *(const h8*)(&sK1[(     c15)*512 + p0]);
    h8 bf1 = *(const h8*)(&sK1[(16 + c15)*512 + p0]);
    h8 bf2 = *(const h8*)(&sK1[(32 + c15)*512 + p0]);
    h8 bf3 = *(const h8*)(&sK1[(48 + c15)*512 + p0]);
    int aoff = step*32 + g*8;
    h8 k = kf[step];
    #pragma unroll
    for (int s = 0; s < 8; ++s){
      h8 av = *(const h8*)(&sAv[s*512 + aoff]);
      h8 ap = k*av;
      acc[0][s] = __builtin_amdgcn_mfma_f32_16x16x32_f16(ap, bf0, acc[0][s], 0, 0, 0);
      acc[1][s] = __builtin_amdgcn_mfma_f32_16x16x32_f16(ap, bf1, acc[1][s], 0, 0, 0);
      acc[2][s] = __builtin_amdgcn_mfma_f32_16x16x32_f16(ap, bf2, acc[2][s], 0, 0, 0);
      acc[3][s] = __builtin_amdgcn_mfma_f32_16x16x32_f16(ap, bf3, acc[3][s], 0, 0, 0);
    }
  }
  #pragma unroll
  for (int s = 0; s < 8; ++s){
    float part = 0.f;
    #pragma unroll
    for (int tt = 0; tt < 4; ++tt){
      float ci = (float)ch[(size_t)(n0+s)*M_ + i0 + tt*16 + c15];
      f32x4 a = acc[tt][s];
      part += ci*(a[0]*a[0] + a[1]*a[1] + a[2]*a[2] + a[3]*a[3]);
    }
    for (int m=32;m>=1;m>>=1) part += __shfl_xor(part, m);
    if (l == 0) atomicAdd(&trH0[n0+s], part);
  }
}

// ---------------- final: grad, outputs (sums z0 partials; adds symA trace) ----------
__global__ void finalk(const float* __restrict__ x, const float* __restrict__ tptr,
                       const float* __restrict__ symA, const float* __restrict__ c_w,
                       const float* __restrict__ z0p, const float* __restrict__ trH0,
                       float* out){
  __shared__ float sA[DP1*DP1];
  int t = threadIdx.x;
  for (int i = t; i < DP1*DP1; i += 256) sA[i] = symA[i];
  __syncthreads();
  int wv = t>>6, l = t&63;
  int n = blockIdx.x*4 + wv;
  float tval = tptr[0];
  float sv = x[n*64 + l];
  float z0l = z0p[(size_t)0*N_*80 + n*80 + l] + z0p[(size_t)1*N_*80 + n*80 + l]
            + z0p[(size_t)2*N_*80 + n*80 + l] + z0p[(size_t)3*N_*80 + n*80 + l];
  float z0t = z0p[(size_t)0*N_*80 + n*80 + 64] + z0p[(size_t)1*N_*80 + n*80 + 64]
            + z0p[(size_t)2*N_*80 + n*80 + 64] + z0p[(size_t)3*N_*80 + n*80 + 64];
  float acc = z0l + c_w[l];
  for (int e = 0; e < 64; ++e){
    float se = __shfl(sv, e);
    acc += se * sA[l*DP1 + e];     // symA symmetric
  }
  acc += tval * sA[l*DP1 + 64];
  // trace(symA[:64,:64]) in-register
  float trd = sA[l*66];
  for (int m=32;m>=1;m>>=1) trd += __shfl_xor(trd, m);
  // grad[64]
  float g64 = sv * sA[64*DP1 + l];
  for (int m=32;m>=1;m>>=1) g64 += __shfl_xor(g64, m);
  g64 += tval*sA[64*DP1+64] + z0t + c_w[64];
  float dz = -acc;
  out[n*64 + l] = dz;
  float q = dz*dz;
  for (int m=32;m>=1;m>>=1) q += __shfl_xor(q, m);
  float costL = 0.5f*q;
  if (l == 0){
    out[N_*64 + n]        = -(trH0[n] + trd);
    out[N_*64 + N_ + n]   = costL;
    out[N_*64 + 2*N_ + n] = fabsf(-g64 + costL);
  }
}

extern "C" void kernel_launch(void* const* d_in, const int* in_sizes, int n_in,
                              void* d_out, int out_size, void* d_ws, size_t ws_size,
                              hipStream_t stream){
  const float* x   = (const float*)d_in[0];
  const float* tp  = (const float*)d_in[1];
  const float* K0  = (const float*)d_in[2];
  const float* b0  = (const float*)d_in[3];
  const float* K1  = (const float*)d_in[4];
  const float* b1  = (const float*)d_in[5];
  const float* w   = (const float*)d_in[6];
  const float* A   = (const float*)d_in[7];
  const float* c_w = (const float*)d_in[8];
  float* out = (float*)d_out;

  char* ws = (char*)d_ws;
  size_t off = 0;
  auto alloc = [&](size_t bytes)->void*{
    void* p = ws + off; off += bytes; off = (off + 255) & ~(size_t)255; return p;
  };
  _Float16* K1h   = (_Float16*)alloc(512*512*2);
  _Float16* K1Th  = (_Float16*)alloc(512*512*2);
  _Float16* K0Th  = (_Float16*)alloc(80*512*2);
  float* symA     = (float*)alloc(DP1*DP1*4);
  float* sumK2    = (float*)alloc(512*4);
  _Float16* u0h   = (_Float16*)alloc((size_t)N_*M_*2);
  _Float16* ah    = (_Float16*)alloc((size_t)N_*M_*2);
  _Float16* tl1wh = (_Float16*)alloc((size_t)N_*M_*2);
  _Float16* ch    = (_Float16*)alloc((size_t)N_*M_*2);
  _Float16* az1h  = (_Float16*)alloc((size_t)N_*M_*2);
  float* z0p      = (float*)alloc((size_t)4*N_*80*4);
  float* trH0     = (float*)alloc(N_*4);

  prepk<<<737, 256, 0, stream>>>(A, K0, K1, x, tp, b0, symA, sumK2,
                                 K1h, K1Th, K0Th, u0h, ah, trH0);
  gemm512<0><<<dim3(N_/64, M_/64), 256, 0, stream>>>(u0h, K1h, b1, w, nullptr, nullptr,
                                                     tl1wh, ch, nullptr);
  gemm512<1><<<dim3(N_/64, M_/64), 256, 0, stream>>>(tl1wh, K1Th, nullptr, w, ah, sumK2,
                                                     az1h, nullptr, trH0);
  gemmz0<<<dim3(N_/64, 4), 256, 0, stream>>>(az1h, K0Th, z0p);
  kjk13<<<dim3(N_/8, 8), 256, 0, stream>>>(K1h, K0Th, ah, ch, trH0);
  finalk<<<N_/4, 256, 0, stream>>>(x, tp, symA, c_w, z0p, trH0, out);
}

// Round 18
// 188.943 us; speedup vs baseline: 1.3939x; 1.0656x over previous
//
#include <hip/hip_runtime.h>
#include <stdint.h>

#define D_  64
#define DP1 65
#define M_  512
#define N_  4096

typedef float f32x4 __attribute__((ext_vector_type(4)));
typedef _Float16 h8 __attribute__((ext_vector_type(8)));

// ---------------- merged prep: symA/sumK2/trH0 | K1 cvt+T | K0T | K0h96 | sxh96 ------
__global__ void prepk(const float* __restrict__ A, const float* __restrict__ K0,
                      const float* __restrict__ K1, const float* __restrict__ x,
                      const float* __restrict__ tptr,
                      float* symA, float* sumK2,
                      _Float16* K1h, _Float16* K1Th, _Float16* K0Th,
                      _Float16* K0h, _Float16* sxh, float* trH0){
  __shared__ float shm[64*66];
  int b = blockIdx.x;
  int t = threadIdx.x;
  if (b == 0){
    for (int idx = t; idx < DP1*DP1; idx += 256){
      int e = idx / DP1, d = idx % DP1;
      float s = 0.f;
      for (int r = 0; r < 10; ++r) s += A[r*DP1+e]*A[r*DP1+d];
      symA[idx] = s;
    }
    for (int m = t; m < M_; m += 256){
      float s = 0.f;
      for (int k = 0; k < D_; ++k){ float v = K0[m*DP1+k]; s += v*v; }
      sumK2[m] = s;
    }
    for (int i = t; i < N_; i += 256) trH0[i] = 0.f;
  } else if (b < 65){
    int bb = b - 1;
    int r0 = (bb>>3)*64, c0 = (bb&7)*64;
    float* tile = shm;                       // [64][65] (fits in [64][66])
    for (int it = 0; it < 16; ++it){
      int lin = it*256 + t;
      int r = lin >> 6, c = lin & 63;
      float v = K1[(r0+r)*M_ + c0+c];
      tile[r*65+c] = v;
      K1h[(r0+r)*M_ + c0+c] = (_Float16)v;
    }
    __syncthreads();
    for (int it = 0; it < 16; ++it){
      int lin = it*256 + t;
      int r = lin >> 6, c = lin & 63;
      K1Th[(c0+r)*M_ + (r0+c)] = (_Float16)tile[c*65+r];
    }
  } else if (b < 225){
    // K0Th: 80 x 512, rows 65..79 zero
    int idx = (b-65)*256 + t;
    if (idx < 80*M_){
      int d = idx / M_, i = idx % M_;
      float v = (d < DP1) ? K0[i*DP1 + d] : 0.f;
      K0Th[idx] = (_Float16)v;
    }
  } else if (b < 249){
    // K0h96: 512 x 96 row-major f16, cols 65..95 zero (6144 h8 chunks / 24 blocks)
    int id = (b-225)*256 + t;
    int i = id / 12, cc = id % 12, c0 = cc*8;
    h8 v;
    #pragma unroll
    for (int e = 0; e < 8; ++e){
      int d = c0 + e;
      v[e] = (d < DP1) ? (_Float16)K0[i*DP1 + d] : (_Float16)0.f;
    }
    *(h8*)(&K0h[(size_t)i*96 + c0]) = v;
  } else {
    // sxh96: 4096 x 96 row-major f16; cols 0..63 = x, col 64 = t, 65..95 zero
    // (49152 h8 chunks / 192 blocks)
    int id = (b-249)*256 + t;
    int n = id / 12, cc = id % 12, c0 = cc*8;
    float tval = tptr[0];
    h8 v;
    #pragma unroll
    for (int e = 0; e < 8; ++e){
      int d = c0 + e;
      float f = (d < 64) ? x[(size_t)n*64 + d] : ((d == 64) ? tval : 0.f);
      v[e] = (_Float16)f;
    }
    *(h8*)(&sxh[(size_t)n*96 + c0]) = v;
  }
}

// ---------------- opening via MFMA: o = s @ K0^T + b0 ; u0, a epilogue --------------
// Fragment pattern identical to gemmz0 (verified); epilogue indexing identical to
// gemm512 MODE 0 (verified). K padded to 96 with zeros (exact).
__launch_bounds__(256, 4)
__global__ void openm(const _Float16* __restrict__ sxh, const _Float16* __restrict__ K0h,
                      const float* __restrict__ b0,
                      _Float16* u0h, _Float16* ah){
  int n0 = blockIdx.x*64, m0 = blockIdx.y*64;
  int t = threadIdx.x, wv = t>>6, l = t&63;
  int r15 = l & 15;
  int krow = (l>>4)*8;
  const _Float16* abase = sxh + (size_t)(n0 + wv*16 + r15)*96 + krow;
  const _Float16* kb0 = K0h + (size_t)(m0 +  0 + r15)*96 + krow;
  const _Float16* kb1 = K0h + (size_t)(m0 + 16 + r15)*96 + krow;
  const _Float16* kb2 = K0h + (size_t)(m0 + 32 + r15)*96 + krow;
  const _Float16* kb3 = K0h + (size_t)(m0 + 48 + r15)*96 + krow;
  f32x4 zero = {0.f,0.f,0.f,0.f};
  f32x4 acc[4]; for (int k=0;k<4;++k) acc[k]=zero;
  #pragma unroll
  for (int ii = 0; ii < 3; ++ii){
    const int j0 = ii*32;
    h8 af  = *(const h8*)(abase + j0);
    h8 b0c = *(const h8*)(kb0 + j0);
    h8 b1c = *(const h8*)(kb1 + j0);
    h8 b2c = *(const h8*)(kb2 + j0);
    h8 b3c = *(const h8*)(kb3 + j0);
    acc[0] = __builtin_amdgcn_mfma_f32_16x16x32_f16(af, b0c, acc[0], 0, 0, 0);
    acc[1] = __builtin_amdgcn_mfma_f32_16x16x32_f16(af, b1c, acc[1], 0, 0, 0);
    acc[2] = __builtin_amdgcn_mfma_f32_16x16x32_f16(af, b2c, acc[2], 0, 0, 0);
    acc[3] = __builtin_amdgcn_mfma_f32_16x16x32_f16(af, b3c, acc[3], 0, 0, 0);
  }
  for (int kt=0;kt<4;++kt) for (int r=0;r<4;++r){
    int n = n0+wv*16+(l>>4)*4+r;
    int m = m0+kt*16+r15;
    float o = acc[kt][r] + b0[m];
    float a = tanhf(o);
    float ax = fabsf(o);
    float u0 = ax + log1pf(expf(-2.f*ax));
    u0h[(size_t)n*M_+m] = (_Float16)u0;
    ah[(size_t)n*M_+m]  = (_Float16)a;
  }
}

// ---------------- 4096x512x512 GEMMs (MODE 0: lin1, MODE 1: z1) ----------------
template<int MODE>
__launch_bounds__(256, 2)
__global__ void gemm512(const _Float16* __restrict__ Ah, const _Float16* __restrict__ Wh,
                        const float* __restrict__ bias, const float* __restrict__ w,
                        const _Float16* __restrict__ ah, const float* __restrict__ sumK2,
                        _Float16* out0, _Float16* out1, float* trH0){
  __shared__ _Float16 sW[64*512];    // 64 KB, chunk-swizzled (c ^ (r&7))
  int n0 = blockIdx.x*64, i0 = blockIdx.y*64;
  int t = threadIdx.x;
  int wv = t>>6, l = t&63;
  int c15 = l & 15, g = l>>4;
  h8 af[16];
  {
    const _Float16* ap = Ah + (size_t)(n0 + wv*16 + c15)*M_ + g*8;
    #pragma unroll
    for (int tt = 0; tt < 16; ++tt) af[tt] = *(const h8*)(ap + tt*32);
  }
  #pragma unroll
  for (int it = 0; it < 16; ++it){
    int r = it*4 + wv;
    const _Float16* src = Wh + (size_t)(i0 + r)*M_ + ((l ^ (r & 7))*8);
    __builtin_amdgcn_global_load_lds(
        (const __attribute__((address_space(1))) void*)src,
        (__attribute__((address_space(3))) void*)(&sW[r*512]), 16, 0, 0);
  }
  __syncthreads();
  f32x4 zero = {0.f,0.f,0.f,0.f};
  f32x4 acc[4]; for (int k=0;k<4;++k) acc[k]=zero;
  #pragma unroll
  for (int step = 0; step < 16; ++step){
    int p0 = (((step*4 + g) ^ (c15 & 7))*8);
    h8 bf0 = *(const h8*)(&sW[(     c15)*512 + p0]);
    h8 bf1 = *(const h8*)(&sW[(16 + c15)*512 + p0]);
    h8 bf2 = *(const h8*)(&sW[(32 + c15)*512 + p0]);
    h8 bf3 = *(const h8*)(&sW[(48 + c15)*512 + p0]);
    h8 a = af[step];
    acc[0] = __builtin_amdgcn_mfma_f32_16x16x32_f16(a, bf0, acc[0], 0, 0, 0);
    acc[1] = __builtin_amdgcn_mfma_f32_16x16x32_f16(a, bf1, acc[1], 0, 0, 0);
    acc[2] = __builtin_amdgcn_mfma_f32_16x16x32_f16(a, bf2, acc[2], 0, 0, 0);
    acc[3] = __builtin_amdgcn_mfma_f32_16x16x32_f16(a, bf3, acc[3], 0, 0, 0);
  }
  if (MODE == 0){
    for (int kt=0;kt<4;++kt) for (int r=0;r<4;++r){
      int n = n0+wv*16+(l>>4)*4+r;
      int i = i0+kt*16+c15;
      float v = acc[kt][r] + bias[i];
      float tl = tanhf(v);
      out0[n*M_+i] = (_Float16)(tl*w[i]);
      out1[n*M_+i] = (_Float16)((1.f-tl*tl)*w[i]);
    }
  } else {
    for (int r=0;r<4;++r){
      int n = n0+wv*16+(l>>4)*4+r;
      float rowpart = 0.f;
      for (int kt=0;kt<4;++kt){
        int i = i0+kt*16+c15;
        float z1 = acc[kt][r] + w[i];
        float a = (float)ah[n*M_+i];
        out0[n*M_+i] = (_Float16)(a*z1);
        rowpart += (1.f-a*a)*z1*sumK2[i];
      }
      for (int m=1;m<16;m<<=1) rowpart += __shfl_xor(rowpart, m);
      if (c15==0) atomicAdd(&trH0[n], rowpart);
    }
  }
}

// ---------------- z0 partials = az1 @ K0 over K-quarter (N x 80, K=128) --------------
__launch_bounds__(256, 4)
__global__ void gemmz0(const _Float16* __restrict__ az1h, const _Float16* __restrict__ K0Th,
                       float* z0p){
  int n0 = blockIdx.x*64;
  int q  = blockIdx.y;               // K-quarter
  int t = threadIdx.x, wv = t>>6, l = t&63;
  int r15 = l & 15;
  int krow = q*128 + (l>>4)*8;
  const _Float16* abase = az1h + (size_t)(n0 + wv*16 + r15)*M_ + krow;
  const _Float16* kb0 = K0Th + (size_t)( 0 + r15)*M_ + krow;
  const _Float16* kb1 = K0Th + (size_t)(16 + r15)*M_ + krow;
  const _Float16* kb2 = K0Th + (size_t)(32 + r15)*M_ + krow;
  const _Float16* kb3 = K0Th + (size_t)(48 + r15)*M_ + krow;
  const _Float16* kb4 = K0Th + (size_t)(64 + r15)*M_ + krow;
  f32x4 zero = {0.f,0.f,0.f,0.f};
  f32x4 acc[5]; for (int k=0;k<5;++k) acc[k]=zero;
  #pragma unroll
  for (int ii = 0; ii < 4; ++ii){
    const int j0 = ii*32;
    h8 af = *(const h8*)(abase + j0);
    h8 b0c = *(const h8*)(kb0 + j0);
    h8 b1c = *(const h8*)(kb1 + j0);
    h8 b2c = *(const h8*)(kb2 + j0);
    h8 b3c = *(const h8*)(kb3 + j0);
    h8 b4c = *(const h8*)(kb4 + j0);
    acc[0] = __builtin_amdgcn_mfma_f32_16x16x32_f16(af, b0c, acc[0], 0, 0, 0);
    acc[1] = __builtin_amdgcn_mfma_f32_16x16x32_f16(af, b1c, acc[1], 0, 0, 0);
    acc[2] = __builtin_amdgcn_mfma_f32_16x16x32_f16(af, b2c, acc[2], 0, 0, 0);
    acc[3] = __builtin_amdgcn_mfma_f32_16x16x32_f16(af, b3c, acc[3], 0, 0, 0);
    acc[4] = __builtin_amdgcn_mfma_f32_16x16x32_f16(af, b4c, acc[4], 0, 0, 0);
  }
  float* zp = z0p + (size_t)q*N_*80;
  for (int dt=0; dt<5; ++dt) for (int r=0;r<4;++r){
    int n = n0+wv*16+(l>>4)*4+r;
    int d = dt*16+r15;
    zp[n*80+d] = acc[dt][r];
  }
}

// ---------------- dominant: t1 partials (kjk13, unchanged) ---------------------------
__launch_bounds__(256, 2)
__global__ void kjk13(const _Float16* __restrict__ K1h, const _Float16* __restrict__ K0Th,
                      const _Float16* __restrict__ ah, const _Float16* __restrict__ ch,
                      float* trH0){
  __shared__ _Float16 sK1[64*512];   // 64 KB, chunk-swizzled (c ^ (r&7))
  __shared__ _Float16 sAv[8*512];    // 8 KB
  int t = threadIdx.x;
  int n0 = blockIdx.x*8;             // 8 samples
  int i0 = blockIdx.y*64;            // 64 K1 rows
  int wv = t>>6, l = t&63;
  int c15 = l & 15, g = l>>4;
  h8 kf[16];
  {
    const _Float16* kfp = K0Th + (size_t)(wv*16 + c15)*M_ + g*8;
    #pragma unroll
    for (int tt = 0; tt < 16; ++tt) kf[tt] = *(const h8*)(kfp + tt*32);
  }
  #pragma unroll
  for (int it = 0; it < 16; ++it){
    int r = it*4 + wv;
    const _Float16* src = K1h + (size_t)(i0 + r)*M_ + ((l ^ (r & 7))*8);
    __builtin_amdgcn_global_load_lds(
        (const __attribute__((address_space(1))) void*)src,
        (__attribute__((address_space(3))) void*)(&sK1[r*512]), 16, 0, 0);
  }
  #pragma unroll
  for (int it = 0; it < 2; ++it){
    int cc = it*256 + t;
    int s = cc >> 6, c = cc & 63;
    *(h8*)(&sAv[s*512 + c*8]) = *(const h8*)(ah + (size_t)(n0+s)*M_ + c*8);
  }
  __syncthreads();
  f32x4 zero = {0.f,0.f,0.f,0.f};
  f32x4 acc[4][8];
  #pragma unroll
  for (int tt=0;tt<4;++tt)
    #pragma unroll
    for (int s=0;s<8;++s) acc[tt][s]=zero;
  #pragma unroll
  for (int step = 0; step < 16; ++step){
    int p0 = (((step*4 + g) ^ (c15 & 7))*8);
    h8 bf0 = *(const h8*)(&sK1[(     c15)*512 + p0]);
    h8 bf1 = *(const h8*)(&sK1[(16 + c15)*512 + p0]);
    h8 bf2 = *(const h8*)(&sK1[(32 + c15)*512 + p0]);
    h8 bf3 = *(const h8*)(&sK1[(48 + c15)*512 + p0]);
    int aoff = step*32 + g*8;
    h8 k = kf[step];
    #pragma unroll
    for (int s = 0; s < 8; ++s){
      h8 av = *(const h8*)(&sAv[s*512 + aoff]);
      h8 ap = k*av;
      acc[0][s] = __builtin_amdgcn_mfma_f32_16x16x32_f16(ap, bf0, acc[0][s], 0, 0, 0);
      acc[1][s] = __builtin_amdgcn_mfma_f32_16x16x32_f16(ap, bf1, acc[1][s], 0, 0, 0);
      acc[2][s] = __builtin_amdgcn_mfma_f32_16x16x32_f16(ap, bf2, acc[2][s], 0, 0, 0);
      acc[3][s] = __builtin_amdgcn_mfma_f32_16x16x32_f16(ap, bf3, acc[3][s], 0, 0, 0);
    }
  }
  #pragma unroll
  for (int s = 0; s < 8; ++s){
    float part = 0.f;
    #pragma unroll
    for (int tt = 0; tt < 4; ++tt){
      float ci = (float)ch[(size_t)(n0+s)*M_ + i0 + tt*16 + c15];
      f32x4 a = acc[tt][s];
      part += ci*(a[0]*a[0] + a[1]*a[1] + a[2]*a[2] + a[3]*a[3]);
    }
    for (int m=32;m>=1;m>>=1) part += __shfl_xor(part, m);
    if (l == 0) atomicAdd(&trH0[n0+s], part);
  }
}

// ---------------- final: grad, outputs (sums z0 partials; adds symA trace) ----------
__global__ void finalk(const float* __restrict__ x, const float* __restrict__ tptr,
                       const float* __restrict__ symA, const float* __restrict__ c_w,
                       const float* __restrict__ z0p, const float* __restrict__ trH0,
                       float* out){
  __shared__ float sA[DP1*DP1];
  int t = threadIdx.x;
  for (int i = t; i < DP1*DP1; i += 256) sA[i] = symA[i];
  __syncthreads();
  int wv = t>>6, l = t&63;
  int n = blockIdx.x*4 + wv;
  float tval = tptr[0];
  float sv = x[n*64 + l];
  float z0l = z0p[(size_t)0*N_*80 + n*80 + l] + z0p[(size_t)1*N_*80 + n*80 + l]
            + z0p[(size_t)2*N_*80 + n*80 + l] + z0p[(size_t)3*N_*80 + n*80 + l];
  float z0t = z0p[(size_t)0*N_*80 + n*80 + 64] + z0p[(size_t)1*N_*80 + n*80 + 64]
            + z0p[(size_t)2*N_*80 + n*80 + 64] + z0p[(size_t)3*N_*80 + n*80 + 64];
  float acc = z0l + c_w[l];
  for (int e = 0; e < 64; ++e){
    float se = __shfl(sv, e);
    acc += se * sA[l*DP1 + e];     // symA symmetric
  }
  acc += tval * sA[l*DP1 + 64];
  // trace(symA[:64,:64]) in-register
  float trd = sA[l*66];
  for (int m=32;m>=1;m>>=1) trd += __shfl_xor(trd, m);
  // grad[64]
  float g64 = sv * sA[64*DP1 + l];
  for (int m=32;m>=1;m>>=1) g64 += __shfl_xor(g64, m);
  g64 += tval*sA[64*DP1+64] + z0t + c_w[64];
  float dz = -acc;
  out[n*64 + l] = dz;
  float q = dz*dz;
  for (int m=32;m>=1;m>>=1) q += __shfl_xor(q, m);
  float costL = 0.5f*q;
  if (l == 0){
    out[N_*64 + n]        = -(trH0[n] + trd);
    out[N_*64 + N_ + n]   = costL;
    out[N_*64 + 2*N_ + n] = fabsf(-g64 + costL);
  }
}

extern "C" void kernel_launch(void* const* d_in, const int* in_sizes, int n_in,
                              void* d_out, int out_size, void* d_ws, size_t ws_size,
                              hipStream_t stream){
  const float* x   = (const float*)d_in[0];
  const float* tp  = (const float*)d_in[1];
  const float* K0  = (const float*)d_in[2];
  const float* b0  = (const float*)d_in[3];
  const float* K1  = (const float*)d_in[4];
  const float* b1  = (const float*)d_in[5];
  const float* w   = (const float*)d_in[6];
  const float* A   = (const float*)d_in[7];
  const float* c_w = (const float*)d_in[8];
  float* out = (float*)d_out;

  char* ws = (char*)d_ws;
  size_t off = 0;
  auto alloc = [&](size_t bytes)->void*{
    void* p = ws + off; off += bytes; off = (off + 255) & ~(size_t)255; return p;
  };
  _Float16* K1h   = (_Float16*)alloc(512*512*2);
  _Float16* K1Th  = (_Float16*)alloc(512*512*2);
  _Float16* K0Th  = (_Float16*)alloc(80*512*2);
  _Float16* K0h   = (_Float16*)alloc(512*96*2);
  _Float16* sxh   = (_Float16*)alloc((size_t)N_*96*2);
  float* symA     = (float*)alloc(DP1*DP1*4);
  float* sumK2    = (float*)alloc(512*4);
  _Float16* u0h   = (_Float16*)alloc((size_t)N_*M_*2);
  _Float16* ah    = (_Float16*)alloc((size_t)N_*M_*2);
  _Float16* tl1wh = (_Float16*)alloc((size_t)N_*M_*2);
  _Float16* ch    = (_Float16*)alloc((size_t)N_*M_*2);
  _Float16* az1h  = (_Float16*)alloc((size_t)N_*M_*2);
  float* z0p      = (float*)alloc((size_t)4*N_*80*4);
  float* trH0     = (float*)alloc(N_*4);

  prepk<<<441, 256, 0, stream>>>(A, K0, K1, x, tp, symA, sumK2,
                                 K1h, K1Th, K0Th, K0h, sxh, trH0);
  openm<<<dim3(N_/64, M_/64), 256, 0, stream>>>(sxh, K0h, b0, u0h, ah);
  gemm512<0><<<dim3(N_/64, M_/64), 256, 0, stream>>>(u0h, K1h, b1, w, nullptr, nullptr,
                                                     tl1wh, ch, nullptr);
  gemm512<1><<<dim3(N_/64, M_/64), 256, 0, stream>>>(tl1wh, K1Th, nullptr, w, ah, sumK2,
                                                     az1h, nullptr, trH0);
  gemmz0<<<dim3(N_/64, 4), 256, 0, stream>>>(az1h, K0Th, z0p);
  kjk13<<<dim3(N_/8, 8), 256, 0, stream>>>(K1h, K0Th, ah, ch, trH0);
  finalk<<<N_/4, 256, 0, stream>>>(x, tp, symA, c_w, z0p, trH0, out);
}